// Round 2
// baseline (1081.965 us; speedup 1.0000x reference)
//
#include <hip/hip_runtime.h>
#include <math.h>

#define NEG_SLOPE 0.2f
#define GAT_EPS 1e-16f

// ---------------------------------------------------------------------------
// Kernel 1: xl1 = x @ W1  [N,64]; as1[n,h] = sum_c xl1[n,h*8+c]*a_src1[h*8+c];
// ad1 likewise. One thread per node; W1 (128x64, 32 KB) staged in LDS.
// ---------------------------------------------------------------------------
__global__ __launch_bounds__(256) void k_gemm1(
    const float* __restrict__ x, const float* __restrict__ W1,
    const float* __restrict__ a_src1, const float* __restrict__ a_dst1,
    float* __restrict__ xl1, float* __restrict__ as1, float* __restrict__ ad1,
    int N, int F)
{
    __shared__ float Ws[128 * 64];
    __shared__ float asrc[64];
    __shared__ float adst[64];
    for (int i = threadIdx.x; i < F * 64; i += 256) Ws[i] = W1[i];
    if (threadIdx.x < 64) {
        asrc[threadIdx.x] = a_src1[threadIdx.x];
        adst[threadIdx.x] = a_dst1[threadIdx.x];
    }
    __syncthreads();

    int n = blockIdx.x * 256 + threadIdx.x;
    if (n >= N) return;

    float acc[64];
#pragma unroll
    for (int c = 0; c < 64; c++) acc[c] = 0.0f;

    const float* xr = x + (size_t)n * F;
    for (int k = 0; k < F; k++) {
        float xk = xr[k];
#pragma unroll
        for (int c = 0; c < 64; c++) acc[c] = fmaf(xk, Ws[k * 64 + c], acc[c]);
    }

    float* xo = xl1 + (size_t)n * 64;
#pragma unroll
    for (int c = 0; c < 64; c++) xo[c] = acc[c];

#pragma unroll
    for (int h = 0; h < 8; h++) {
        float s = 0.0f, t = 0.0f;
#pragma unroll
        for (int c = 0; c < 8; c++) {
            s = fmaf(acc[h * 8 + c], asrc[h * 8 + c], s);
            t = fmaf(acc[h * 8 + c], adst[h * 8 + c], t);
        }
        as1[(size_t)n * 8 + h] = s;
        ad1[(size_t)n * 8 + h] = t;
    }
}

// ---------------------------------------------------------------------------
// Kernel 2: edge pass layer 1. One wave (64 lanes) per edge; lane = channel.
// Accumulates unnormalized softmax numerator into acc1[dst,64] and
// denominator into denom1[dst,8] with native fp32 atomics.
// Edge ids e >= E are the self-loops (s = d = e - E).
// edge_index is int32 on device (harness materializes integers as int).
// ---------------------------------------------------------------------------
__global__ __launch_bounds__(256) void k_edge1(
    const int* __restrict__ ei, int E, int N,
    const float* __restrict__ as1, const float* __restrict__ ad1,
    const float* __restrict__ xl1,
    float* __restrict__ acc1, float* __restrict__ denom1)
{
    int Etot = E + N;
    int e = blockIdx.x * 4 + (threadIdx.x >> 6);
    int lane = threadIdx.x & 63;
    if (e >= Etot) return;

    int s, d;
    if (e < E) { s = ei[e]; d = ei[E + e]; }
    else       { s = e - E; d = s; }

    int h = lane >> 3;
    float al = as1[(size_t)s * 8 + h] + ad1[(size_t)d * 8 + h];
    al = al > 0.0f ? al : NEG_SLOPE * al;
    float eh = __expf(al);

    unsafeAtomicAdd(&acc1[(size_t)d * 64 + lane],
                    eh * xl1[(size_t)s * 64 + lane]);

    if (lane < 8) {
        float al2 = as1[(size_t)s * 8 + lane] + ad1[(size_t)d * 8 + lane];
        al2 = al2 > 0.0f ? al2 : NEG_SLOPE * al2;
        unsafeAtomicAdd(&denom1[(size_t)d * 8 + lane], __expf(al2));
    }
}

// ---------------------------------------------------------------------------
// Kernel 3 (fused): h = elu(acc1/denom1 + b1); xl2 = h @ W2 [N,40];
// as2[n] = xl2 . a_src2; ad2[n] = xl2 . a_dst2. Thread per node; W2 in LDS.
// ---------------------------------------------------------------------------
__global__ __launch_bounds__(256) void k_node2(
    const float* __restrict__ acc1, const float* __restrict__ denom1,
    const float* __restrict__ b1, const float* __restrict__ W2,
    const float* __restrict__ a_src2, const float* __restrict__ a_dst2,
    float* __restrict__ xl2, float* __restrict__ as2, float* __restrict__ ad2,
    int N)
{
    __shared__ float Ws[64 * 40];
    __shared__ float b1s[64];
    __shared__ float a2s[40];
    __shared__ float a2d[40];
    for (int i = threadIdx.x; i < 64 * 40; i += 256) Ws[i] = W2[i];
    if (threadIdx.x < 64) b1s[threadIdx.x] = b1[threadIdx.x];
    if (threadIdx.x < 40) {
        a2s[threadIdx.x] = a_src2[threadIdx.x];
        a2d[threadIdx.x] = a_dst2[threadIdx.x];
    }
    __syncthreads();

    int n = blockIdx.x * 256 + threadIdx.x;
    if (n >= N) return;

    float dn[8];
#pragma unroll
    for (int h = 0; h < 8; h++)
        dn[h] = 1.0f / (denom1[(size_t)n * 8 + h] + GAT_EPS);

    float o[40];
#pragma unroll
    for (int j = 0; j < 40; j++) o[j] = 0.0f;

    const float* ar = acc1 + (size_t)n * 64;
    for (int k = 0; k < 64; k++) {
        float hk = ar[k] * dn[k >> 3] + b1s[k];
        hk = hk > 0.0f ? hk : expm1f(hk);  // ELU, alpha=1
#pragma unroll
        for (int j = 0; j < 40; j++) o[j] = fmaf(hk, Ws[k * 40 + j], o[j]);
    }

    float s = 0.0f, t = 0.0f;
    float* xo = xl2 + (size_t)n * 40;
#pragma unroll
    for (int j = 0; j < 40; j++) {
        s = fmaf(o[j], a2s[j], s);
        t = fmaf(o[j], a2d[j], t);
        xo[j] = o[j];
    }
    as2[n] = s;
    ad2[n] = t;
}

// ---------------------------------------------------------------------------
// Kernel 4: edge pass layer 2 (H=1, C=40). Wave per edge; lanes 0..39 active.
// ---------------------------------------------------------------------------
__global__ __launch_bounds__(256) void k_edge2(
    const int* __restrict__ ei, int E, int N,
    const float* __restrict__ as2, const float* __restrict__ ad2,
    const float* __restrict__ xl2,
    float* __restrict__ acc2, float* __restrict__ denom2)
{
    int Etot = E + N;
    int e = blockIdx.x * 4 + (threadIdx.x >> 6);
    int lane = threadIdx.x & 63;
    if (e >= Etot) return;

    int s, d;
    if (e < E) { s = ei[e]; d = ei[E + e]; }
    else       { s = e - E; d = s; }

    float al = as2[s] + ad2[d];
    al = al > 0.0f ? al : NEG_SLOPE * al;
    float ev = __expf(al);

    if (lane < 40)
        unsafeAtomicAdd(&acc2[(size_t)d * 40 + lane],
                        ev * xl2[(size_t)s * 40 + lane]);
    if (lane == 0) unsafeAtomicAdd(&denom2[d], ev);
}

// ---------------------------------------------------------------------------
// Kernel 5: out = acc2 / (denom2 + eps) + b2. Thread per output element.
// ---------------------------------------------------------------------------
__global__ __launch_bounds__(256) void k_node3(
    const float* __restrict__ acc2, const float* __restrict__ denom2,
    const float* __restrict__ b2, float* __restrict__ out, int N)
{
    int i = blockIdx.x * 256 + threadIdx.x;
    if (i >= N * 40) return;
    int n = i / 40;
    int j = i - n * 40;
    out[i] = acc2[i] / (denom2[n] + GAT_EPS) + b2[j];
}

extern "C" void kernel_launch(void* const* d_in, const int* in_sizes, int n_in,
                              void* d_out, int out_size, void* d_ws, size_t ws_size,
                              hipStream_t stream) {
    const float* x      = (const float*)d_in[0];
    const int*   ei     = (const int*)d_in[1];     // int32 on device
    const float* W1     = (const float*)d_in[2];
    const float* a_src1 = (const float*)d_in[3];
    const float* a_dst1 = (const float*)d_in[4];
    const float* b1     = (const float*)d_in[5];
    const float* W2     = (const float*)d_in[6];
    const float* a_src2 = (const float*)d_in[7];
    const float* a_dst2 = (const float*)d_in[8];
    const float* b2     = (const float*)d_in[9];

    int F = in_sizes[2] / 64;      // 128
    int N = in_sizes[0] / F;       // 100000
    int E = in_sizes[1] / 2;       // 1600000
    int Etot = E + N;

    // Workspace layout (floats), with layer-2 buffers aliased onto dead
    // layer-1 buffers. Peak footprint: N*152 floats = 60.8 MB.
    float* ws     = (float*)d_ws;
    float* xl1    = ws;                              // N*64
    float* as1    = xl1 + (size_t)N * 64;            // N*8
    float* ad1    = as1 + (size_t)N * 8;             // N*8
    float* denom1 = ad1 + (size_t)N * 8;             // N*8
    float* acc1   = denom1 + (size_t)N * 8;          // N*64
    // Aliases (live only after k_node2; originals dead by then):
    float* xl2    = xl1;                             // N*40 <= N*64
    float* as2    = as1;                             // N
    float* ad2    = ad1;                             // N
    float* denom2 = denom1;                          // N
    float* acc2   = acc1;                            // N*40 <= N*64

    // Zero layer-1 accumulators (ws is poisoned 0xAA before every launch).
    hipMemsetAsync(denom1, 0, (size_t)N * 8 * sizeof(float), stream);
    hipMemsetAsync(acc1,   0, (size_t)N * 64 * sizeof(float), stream);

    k_gemm1<<<(N + 255) / 256, 256, 0, stream>>>(x, W1, a_src1, a_dst1,
                                                 xl1, as1, ad1, N, F);

    k_edge1<<<(Etot + 3) / 4, 256, 0, stream>>>(ei, E, N, as1, ad1, xl1,
                                                acc1, denom1);

    k_node2<<<(N + 255) / 256, 256, 0, stream>>>(acc1, denom1, b1, W2,
                                                 a_src2, a_dst2,
                                                 xl2, as2, ad2, N);

    // Zero layer-2 accumulators (aliased regions are dead after k_node2;
    // stream ordering makes this race-free).
    hipMemsetAsync(denom2, 0, (size_t)N * sizeof(float), stream);
    hipMemsetAsync(acc2,   0, (size_t)N * 40 * sizeof(float), stream);

    k_edge2<<<(Etot + 3) / 4, 256, 0, stream>>>(ei, E, N, as2, ad2, xl2,
                                                acc2, denom2);

    k_node3<<<(N * 40 + 255) / 256, 256, 0, stream>>>(acc2, denom2, b2,
                                                      (float*)d_out, N);
}

// Round 3
// 669.854 us; speedup vs baseline: 1.6152x; 1.6152x over previous
//
#include <hip/hip_runtime.h>
#include <math.h>

#define NEG_SLOPE 0.2f
#define GAT_EPS 1e-16f

// ===========================================================================
// CSR build: deg histogram -> two-level exclusive scan -> scatter by dst.
// Edge ids e in [0, Etot); e >= E are self-loops (s = d = e - E).
// edge_index layout: ei[0..E) = src, ei[E..2E) = dst (int32 on device).
// ===========================================================================

__global__ __launch_bounds__(256) void k_hist(
    const int* __restrict__ ei, int E, int N, int* __restrict__ deg)
{
    int Etot = E + N;
    int e = blockIdx.x * 256 + threadIdx.x;
    if (e >= Etot) return;
    int d = (e < E) ? ei[E + e] : (e - E);
    atomicAdd(&deg[d], 1);
}

// Block sums of deg (256 elements per block).
__global__ __launch_bounds__(256) void k_scan_a(
    const int* __restrict__ deg, int* __restrict__ bsum, int N)
{
    __shared__ int sm[256];
    int i = blockIdx.x * 256 + threadIdx.x;
    sm[threadIdx.x] = (i < N) ? deg[i] : 0;
    __syncthreads();
    for (int s = 128; s > 0; s >>= 1) {
        if (threadIdx.x < s) sm[threadIdx.x] += sm[threadIdx.x + s];
        __syncthreads();
    }
    if (threadIdx.x == 0) bsum[blockIdx.x] = sm[0];
}

// Exclusive scan of block sums (single block, up to 1024 blocks' worth).
__global__ __launch_bounds__(1024) void k_scan_b(
    const int* __restrict__ bsum, int* __restrict__ boff, int NB)
{
    __shared__ int sm[1024];
    int t = threadIdx.x;
    int v0 = (t < NB) ? bsum[t] : 0;
    sm[t] = v0;
    __syncthreads();
    for (int off = 1; off < 1024; off <<= 1) {
        int v = (t >= off) ? sm[t - off] : 0;
        __syncthreads();
        sm[t] += v;
        __syncthreads();
    }
    if (t < NB) boff[t] = sm[t] - v0;  // exclusive
}

// Per-block exclusive scan + block offset -> row_ptr, cursor.
__global__ __launch_bounds__(256) void k_scan_c(
    const int* __restrict__ deg, const int* __restrict__ boff,
    int* __restrict__ row_ptr, int* __restrict__ cursor, int N, int Etot)
{
    __shared__ int sm[256];
    int t = threadIdx.x;
    int i = blockIdx.x * 256 + t;
    int dv = (i < N) ? deg[i] : 0;
    sm[t] = dv;
    __syncthreads();
    for (int off = 1; off < 256; off <<= 1) {
        int v = (t >= off) ? sm[t - off] : 0;
        __syncthreads();
        sm[t] += v;
        __syncthreads();
    }
    int excl = sm[t] - dv + boff[blockIdx.x];
    if (i < N) { row_ptr[i] = excl; cursor[i] = excl; }
    if (i == N - 1) row_ptr[N] = Etot;
}

__global__ __launch_bounds__(256) void k_scatter(
    const int* __restrict__ ei, int E, int N,
    int* __restrict__ cursor, int* __restrict__ csr_src)
{
    int Etot = E + N;
    int e = blockIdx.x * 256 + threadIdx.x;
    if (e >= Etot) return;
    int s, d;
    if (e < E) { s = ei[e]; d = ei[E + e]; }
    else       { s = e - E; d = s; }
    int pos = atomicAdd(&cursor[d], 1);
    csr_src[pos] = s;
}

// ===========================================================================
// Kernel: xl1 = x @ W1 [N,64]; as1/ad1 attention logits per head.
// Thread per node; W1 (128x64, 32 KB) staged in LDS.
// ===========================================================================
__global__ __launch_bounds__(256) void k_gemm1(
    const float* __restrict__ x, const float* __restrict__ W1,
    const float* __restrict__ a_src1, const float* __restrict__ a_dst1,
    float* __restrict__ xl1, float* __restrict__ as1, float* __restrict__ ad1,
    int N, int F)
{
    __shared__ float Ws[128 * 64];
    __shared__ float asrc[64];
    __shared__ float adst[64];
    for (int i = threadIdx.x; i < F * 64; i += 256) Ws[i] = W1[i];
    if (threadIdx.x < 64) {
        asrc[threadIdx.x] = a_src1[threadIdx.x];
        adst[threadIdx.x] = a_dst1[threadIdx.x];
    }
    __syncthreads();

    int n = blockIdx.x * 256 + threadIdx.x;
    if (n >= N) return;

    float acc[64];
#pragma unroll
    for (int c = 0; c < 64; c++) acc[c] = 0.0f;

    const float* xr = x + (size_t)n * F;
    for (int k = 0; k < F; k++) {
        float xk = xr[k];
#pragma unroll
        for (int c = 0; c < 64; c++) acc[c] = fmaf(xk, Ws[k * 64 + c], acc[c]);
    }

    float* xo = xl1 + (size_t)n * 64;
#pragma unroll
    for (int c = 0; c < 64; c++) xo[c] = acc[c];

#pragma unroll
    for (int h = 0; h < 8; h++) {
        float s = 0.0f, t = 0.0f;
#pragma unroll
        for (int c = 0; c < 8; c++) {
            s = fmaf(acc[h * 8 + c], asrc[h * 8 + c], s);
            t = fmaf(acc[h * 8 + c], adst[h * 8 + c], t);
        }
        as1[(size_t)n * 8 + h] = s;
        ad1[(size_t)n * 8 + h] = t;
    }
}

// ===========================================================================
// Layer-1 aggregation, pull-mode: one wave per dst node, lane = channel,
// head = lane>>3. Accumulates numerator and denominator in registers
// (denominator is identical across the 8 lanes of a head), then writes the
// normalized + biased + ELU'd result h1[d,64] once. NO atomics.
// ===========================================================================
__global__ __launch_bounds__(256) void k_agg1(
    const int* __restrict__ row_ptr, const int* __restrict__ csr_src,
    const float* __restrict__ as1, const float* __restrict__ ad1,
    const float* __restrict__ xl1, const float* __restrict__ b1,
    float* __restrict__ h1, int N)
{
    int d = blockIdx.x * 4 + (threadIdx.x >> 6);
    int lane = threadIdx.x & 63;
    if (d >= N) return;
    int h = lane >> 3;

    int beg = row_ptr[d];
    int end = row_ptr[d + 1];
    float adh = ad1[(size_t)d * 8 + h];

    float acc = 0.0f, den = 0.0f;
    int s_next = (beg < end) ? csr_src[beg] : 0;
    for (int i = beg; i < end; i++) {
        int s = s_next;
        if (i + 1 < end) s_next = csr_src[i + 1];
        float al = as1[(size_t)s * 8 + h] + adh;
        al = al > 0.0f ? al : NEG_SLOPE * al;
        float eh = __expf(al);
        acc = fmaf(eh, xl1[(size_t)s * 64 + lane], acc);
        den += eh;
    }

    float hv = acc / (den + GAT_EPS) + b1[lane];
    hv = hv > 0.0f ? hv : expm1f(hv);  // ELU alpha=1
    h1[(size_t)d * 64 + lane] = hv;
}

// ===========================================================================
// Layer-2 node transform: xl2 = h1 @ W2 [N,40]; as2/ad2 logits.
// Thread per node; W2 (64x40) in LDS.
// ===========================================================================
__global__ __launch_bounds__(256) void k_node2(
    const float* __restrict__ h1, const float* __restrict__ W2,
    const float* __restrict__ a_src2, const float* __restrict__ a_dst2,
    float* __restrict__ xl2, float* __restrict__ as2, float* __restrict__ ad2,
    int N)
{
    __shared__ float Ws[64 * 40];
    __shared__ float a2s[40];
    __shared__ float a2d[40];
    for (int i = threadIdx.x; i < 64 * 40; i += 256) Ws[i] = W2[i];
    if (threadIdx.x < 40) {
        a2s[threadIdx.x] = a_src2[threadIdx.x];
        a2d[threadIdx.x] = a_dst2[threadIdx.x];
    }
    __syncthreads();

    int n = blockIdx.x * 256 + threadIdx.x;
    if (n >= N) return;

    float o[40];
#pragma unroll
    for (int j = 0; j < 40; j++) o[j] = 0.0f;

    const float* hr = h1 + (size_t)n * 64;
    for (int k = 0; k < 64; k++) {
        float hk = hr[k];
#pragma unroll
        for (int j = 0; j < 40; j++) o[j] = fmaf(hk, Ws[k * 40 + j], o[j]);
    }

    float s = 0.0f, t = 0.0f;
    float* xo = xl2 + (size_t)n * 40;
#pragma unroll
    for (int j = 0; j < 40; j++) {
        s = fmaf(o[j], a2s[j], s);
        t = fmaf(o[j], a2d[j], t);
        xo[j] = o[j];
    }
    as2[n] = s;
    ad2[n] = t;
}

// ===========================================================================
// Layer-2 aggregation, pull-mode: wave per dst node, lanes 0..39 = channels.
// Writes final output (normalized + b2) directly. NO atomics.
// ===========================================================================
__global__ __launch_bounds__(256) void k_agg2(
    const int* __restrict__ row_ptr, const int* __restrict__ csr_src,
    const float* __restrict__ as2, const float* __restrict__ ad2,
    const float* __restrict__ xl2, const float* __restrict__ b2,
    float* __restrict__ out, int N)
{
    int d = blockIdx.x * 4 + (threadIdx.x >> 6);
    int lane = threadIdx.x & 63;
    if (d >= N) return;

    int beg = row_ptr[d];
    int end = row_ptr[d + 1];
    float add = ad2[d];

    float acc = 0.0f, den = 0.0f;
    int s_next = (beg < end) ? csr_src[beg] : 0;
    for (int i = beg; i < end; i++) {
        int s = s_next;
        if (i + 1 < end) s_next = csr_src[i + 1];
        float al = as2[s] + add;
        al = al > 0.0f ? al : NEG_SLOPE * al;
        float ev = __expf(al);
        if (lane < 40) acc = fmaf(ev, xl2[(size_t)s * 40 + lane], acc);
        den += ev;
    }

    if (lane < 40)
        out[(size_t)d * 40 + lane] = acc / (den + GAT_EPS) + b2[lane];
}

extern "C" void kernel_launch(void* const* d_in, const int* in_sizes, int n_in,
                              void* d_out, int out_size, void* d_ws, size_t ws_size,
                              hipStream_t stream) {
    const float* x      = (const float*)d_in[0];
    const int*   ei     = (const int*)d_in[1];     // int32 on device
    const float* W1     = (const float*)d_in[2];
    const float* a_src1 = (const float*)d_in[3];
    const float* a_dst1 = (const float*)d_in[4];
    const float* b1     = (const float*)d_in[5];
    const float* W2     = (const float*)d_in[6];
    const float* a_src2 = (const float*)d_in[7];
    const float* a_dst2 = (const float*)d_in[8];
    const float* b2     = (const float*)d_in[9];

    int F = in_sizes[2] / 64;      // 128
    int N = in_sizes[0] / F;       // 100000
    int E = in_sizes[1] / 2;       // 1600000
    int Etot = E + N;
    int NB = (N + 255) / 256;      // 391 blocks (<=1024 supported by scan_b)

    // Workspace layout (4-byte words). Layer-2 buffers alias dead layer-1
    // buffers. Peak ~66 MB.
    float* ws      = (float*)d_ws;
    float* xl1     = ws;                             // N*64
    float* h1      = xl1 + (size_t)N * 64;           // N*64
    float* as1     = h1 + (size_t)N * 64;            // N*8
    float* ad1     = as1 + (size_t)N * 8;            // N*8
    int*   deg     = (int*)(ad1 + (size_t)N * 8);    // N
    int*   row_ptr = deg + N;                        // N+1
    int*   cursor  = row_ptr + (N + 1);              // N
    int*   bsum    = cursor + N;                     // 1024
    int*   boff    = bsum + 1024;                    // 1024
    int*   csr_src = boff + 1024;                    // Etot
    // Aliases (live only after k_agg1; originals dead by then):
    float* xl2     = xl1;                            // N*40 <= N*64
    float* as2     = as1;                            // N
    float* ad2     = ad1;                            // N

    // ---- CSR build (shared by both layers) ----
    hipMemsetAsync(deg, 0, (size_t)N * sizeof(int), stream);
    k_hist   <<<(Etot + 255) / 256, 256, 0, stream>>>(ei, E, N, deg);
    k_scan_a <<<NB, 256, 0, stream>>>(deg, bsum, N);
    k_scan_b <<<1, 1024, 0, stream>>>(bsum, boff, NB);
    k_scan_c <<<NB, 256, 0, stream>>>(deg, boff, row_ptr, cursor, N, Etot);
    k_scatter<<<(Etot + 255) / 256, 256, 0, stream>>>(ei, E, N, cursor, csr_src);

    // ---- Layer 1 ----
    k_gemm1<<<(N + 255) / 256, 256, 0, stream>>>(x, W1, a_src1, a_dst1,
                                                 xl1, as1, ad1, N, F);
    k_agg1 <<<(N + 3) / 4, 256, 0, stream>>>(row_ptr, csr_src, as1, ad1,
                                             xl1, b1, h1, N);

    // ---- Layer 2 ----
    k_node2<<<(N + 255) / 256, 256, 0, stream>>>(h1, W2, a_src2, a_dst2,
                                                 xl2, as2, ad2, N);
    k_agg2 <<<(N + 3) / 4, 256, 0, stream>>>(row_ptr, csr_src, as2, ad2,
                                             xl2, b2, (float*)d_out, N);
}

// Round 4
// 513.850 us; speedup vs baseline: 2.1056x; 1.3036x over previous
//
#include <hip/hip_runtime.h>
#include <math.h>

#define NEG_SLOPE 0.2f
#define GAT_EPS 1e-16f

// ---- bf16 pair packing helpers (channel 2p in low half, 2p+1 in high) ----
__device__ __forceinline__ unsigned pack_bf16(float a, float b) {
    unsigned ua = __float_as_uint(a);
    unsigned ub = __float_as_uint(b);
    ua = (ua + 0x8000u) >> 16;          // round-to-nearest-ish
    ub = (ub + 0x8000u) & 0xffff0000u;
    return ua | ub;
}
__device__ __forceinline__ float bf_lo(unsigned pk) {
    return __uint_as_float(pk << 16);
}
__device__ __forceinline__ float bf_hi(unsigned pk) {
    return __uint_as_float(pk & 0xffff0000u);
}

// ===========================================================================
// CSR build: deg histogram -> two-level exclusive scan -> scatter by dst.
// Edge ids e in [0, Etot); e >= E are self-loops (s = d = e - E).
// edge_index layout: ei[0..E) = src, ei[E..2E) = dst (int32 on device).
// ===========================================================================
__global__ __launch_bounds__(256) void k_hist(
    const int* __restrict__ ei, int E, int N, int* __restrict__ deg)
{
    int Etot = E + N;
    int e = blockIdx.x * 256 + threadIdx.x;
    if (e >= Etot) return;
    int d = (e < E) ? ei[E + e] : (e - E);
    atomicAdd(&deg[d], 1);
}

__global__ __launch_bounds__(256) void k_scan_a(
    const int* __restrict__ deg, int* __restrict__ bsum, int N)
{
    __shared__ int sm[256];
    int i = blockIdx.x * 256 + threadIdx.x;
    sm[threadIdx.x] = (i < N) ? deg[i] : 0;
    __syncthreads();
    for (int s = 128; s > 0; s >>= 1) {
        if (threadIdx.x < s) sm[threadIdx.x] += sm[threadIdx.x + s];
        __syncthreads();
    }
    if (threadIdx.x == 0) bsum[blockIdx.x] = sm[0];
}

__global__ __launch_bounds__(1024) void k_scan_b(
    const int* __restrict__ bsum, int* __restrict__ boff, int NB)
{
    __shared__ int sm[1024];
    int t = threadIdx.x;
    int v0 = (t < NB) ? bsum[t] : 0;
    sm[t] = v0;
    __syncthreads();
    for (int off = 1; off < 1024; off <<= 1) {
        int v = (t >= off) ? sm[t - off] : 0;
        __syncthreads();
        sm[t] += v;
        __syncthreads();
    }
    if (t < NB) boff[t] = sm[t] - v0;  // exclusive
}

__global__ __launch_bounds__(256) void k_scan_c(
    const int* __restrict__ deg, const int* __restrict__ boff,
    int* __restrict__ row_ptr, int* __restrict__ cursor, int N, int Etot)
{
    __shared__ int sm[256];
    int t = threadIdx.x;
    int i = blockIdx.x * 256 + t;
    int dv = (i < N) ? deg[i] : 0;
    sm[t] = dv;
    __syncthreads();
    for (int off = 1; off < 256; off <<= 1) {
        int v = (t >= off) ? sm[t - off] : 0;
        __syncthreads();
        sm[t] += v;
        __syncthreads();
    }
    int excl = sm[t] - dv + boff[blockIdx.x];
    if (i < N) { row_ptr[i] = excl; cursor[i] = excl; }
    if (i == N - 1) row_ptr[N] = Etot;
}

__global__ __launch_bounds__(256) void k_scatter(
    const int* __restrict__ ei, int E, int N,
    int* __restrict__ cursor, int* __restrict__ csr_src)
{
    int Etot = E + N;
    int e = blockIdx.x * 256 + threadIdx.x;
    if (e >= Etot) return;
    int s, d;
    if (e < E) { s = ei[e]; d = ei[E + e]; }
    else       { s = e - E; d = s; }
    int pos = atomicAdd(&cursor[d], 1);
    csr_src[pos] = s;
}

// ===========================================================================
// xl1 = x @ W1 [N,64] -> packed bf16 pairs; as1/ad1 logits (f32).
// Thread per node; W1 (32 KB) in LDS; x read as float4.
// ===========================================================================
__global__ __launch_bounds__(256) void k_gemm1(
    const float* __restrict__ x, const float* __restrict__ W1,
    const float* __restrict__ a_src1, const float* __restrict__ a_dst1,
    unsigned* __restrict__ xl1b, float* __restrict__ as1,
    float* __restrict__ ad1, int N, int F)
{
    __shared__ float Ws[128 * 64];
    __shared__ float asrc[64];
    __shared__ float adst[64];
    for (int i = threadIdx.x; i < F * 64; i += 256) Ws[i] = W1[i];
    if (threadIdx.x < 64) {
        asrc[threadIdx.x] = a_src1[threadIdx.x];
        adst[threadIdx.x] = a_dst1[threadIdx.x];
    }
    __syncthreads();

    int n = blockIdx.x * 256 + threadIdx.x;
    if (n >= N) return;

    float acc[64];
#pragma unroll
    for (int c = 0; c < 64; c++) acc[c] = 0.0f;

    const float4* xr4 = (const float4*)(x + (size_t)n * F);
    for (int k4 = 0; k4 < F / 4; k4++) {
        float4 xv = xr4[k4];
        const float* w0 = &Ws[(k4 * 4 + 0) * 64];
        const float* w1 = &Ws[(k4 * 4 + 1) * 64];
        const float* w2 = &Ws[(k4 * 4 + 2) * 64];
        const float* w3 = &Ws[(k4 * 4 + 3) * 64];
#pragma unroll
        for (int c = 0; c < 64; c++) {
            float a = acc[c];
            a = fmaf(xv.x, w0[c], a);
            a = fmaf(xv.y, w1[c], a);
            a = fmaf(xv.z, w2[c], a);
            a = fmaf(xv.w, w3[c], a);
            acc[c] = a;
        }
    }

    unsigned* xo = xl1b + (size_t)n * 32;
#pragma unroll
    for (int p = 0; p < 32; p++) xo[p] = pack_bf16(acc[2 * p], acc[2 * p + 1]);

#pragma unroll
    for (int h = 0; h < 8; h++) {
        float s = 0.0f, t = 0.0f;
#pragma unroll
        for (int c = 0; c < 8; c++) {
            s = fmaf(acc[h * 8 + c], asrc[h * 8 + c], s);
            t = fmaf(acc[h * 8 + c], adst[h * 8 + c], t);
        }
        as1[(size_t)n * 8 + h] = s;
        ad1[(size_t)n * 8 + h] = t;
    }
}

// ===========================================================================
// Layer-1 aggregation (pull). Wave per dst. lane = 32*half + p;
// p = channel-pair (c=2p,2p+1), half-waves take even/odd edges, unroll x2
// -> 4 independent edge gathers in flight. shfl_xor(32) combines halves.
// Fused: normalize + b1 + ELU -> h1[d,64] f32.
// ===========================================================================
__global__ __launch_bounds__(256) void k_agg1(
    const int* __restrict__ row_ptr, const int* __restrict__ csr_src,
    const float* __restrict__ as1, const float* __restrict__ ad1,
    const unsigned* __restrict__ xl1b, const float* __restrict__ b1,
    float* __restrict__ h1, int N)
{
    int d = blockIdx.x * 4 + (threadIdx.x >> 6);
    int lane = threadIdx.x & 63;
    if (d >= N) return;
    int half = lane >> 5;
    int p = lane & 31;          // channel pair
    int h = p >> 2;             // head of channels 2p,2p+1

    int beg = row_ptr[d];
    int end = row_ptr[d + 1];
    float adh = ad1[(size_t)d * 8 + h];

    float ax0 = 0.f, ay0 = 0.f, dn0 = 0.f;
    float ax1 = 0.f, ay1 = 0.f, dn1 = 0.f;
    int i = beg + half;
    for (; i + 2 < end; i += 4) {
        int s0 = csr_src[i];
        int s1 = csr_src[i + 2];
        float al0 = as1[(size_t)s0 * 8 + h] + adh;
        float al1 = as1[(size_t)s1 * 8 + h] + adh;
        unsigned k0 = xl1b[(size_t)s0 * 32 + p];
        unsigned k1 = xl1b[(size_t)s1 * 32 + p];
        al0 = al0 > 0.f ? al0 : NEG_SLOPE * al0;
        al1 = al1 > 0.f ? al1 : NEG_SLOPE * al1;
        float e0 = __expf(al0);
        float e1 = __expf(al1);
        ax0 = fmaf(e0, bf_lo(k0), ax0); ay0 = fmaf(e0, bf_hi(k0), ay0); dn0 += e0;
        ax1 = fmaf(e1, bf_lo(k1), ax1); ay1 = fmaf(e1, bf_hi(k1), ay1); dn1 += e1;
    }
    if (i < end) {
        int s0 = csr_src[i];
        float al0 = as1[(size_t)s0 * 8 + h] + adh;
        unsigned k0 = xl1b[(size_t)s0 * 32 + p];
        al0 = al0 > 0.f ? al0 : NEG_SLOPE * al0;
        float e0 = __expf(al0);
        ax0 = fmaf(e0, bf_lo(k0), ax0); ay0 = fmaf(e0, bf_hi(k0), ay0); dn0 += e0;
    }

    float ax = ax0 + ax1, ay = ay0 + ay1, den = dn0 + dn1;
    ax += __shfl_xor(ax, 32);
    ay += __shfl_xor(ay, 32);
    den += __shfl_xor(den, 32);

    if (half == 0) {
        float inv = 1.0f / (den + GAT_EPS);
        float2 bv = ((const float2*)b1)[p];
        float hx = ax * inv + bv.x;
        float hy = ay * inv + bv.y;
        hx = hx > 0.f ? hx : expm1f(hx);
        hy = hy > 0.f ? hy : expm1f(hy);
        ((float2*)(h1 + (size_t)d * 64))[p] = make_float2(hx, hy);
    }
}

// ===========================================================================
// Layer-2 node transform: xl2 = h1 @ W2 [N,40] -> packed bf16; as2/ad2.
// Thread per node; W2 (64x40) in LDS.
// ===========================================================================
__global__ __launch_bounds__(256) void k_node2(
    const float* __restrict__ h1, const float* __restrict__ W2,
    const float* __restrict__ a_src2, const float* __restrict__ a_dst2,
    unsigned* __restrict__ xl2b, float* __restrict__ as2,
    float* __restrict__ ad2, int N)
{
    __shared__ float Ws[64 * 40];
    __shared__ float a2s[40];
    __shared__ float a2d[40];
    for (int i = threadIdx.x; i < 64 * 40; i += 256) Ws[i] = W2[i];
    if (threadIdx.x < 40) {
        a2s[threadIdx.x] = a_src2[threadIdx.x];
        a2d[threadIdx.x] = a_dst2[threadIdx.x];
    }
    __syncthreads();

    int n = blockIdx.x * 256 + threadIdx.x;
    if (n >= N) return;

    float o[40];
#pragma unroll
    for (int j = 0; j < 40; j++) o[j] = 0.0f;

    const float* hr = h1 + (size_t)n * 64;
    for (int k = 0; k < 64; k++) {
        float hk = hr[k];
#pragma unroll
        for (int j = 0; j < 40; j++) o[j] = fmaf(hk, Ws[k * 40 + j], o[j]);
    }

    float s = 0.0f, t = 0.0f;
    unsigned* xo = xl2b + (size_t)n * 20;
#pragma unroll
    for (int j = 0; j < 40; j++) {
        s = fmaf(o[j], a2s[j], s);
        t = fmaf(o[j], a2d[j], t);
    }
#pragma unroll
    for (int p = 0; p < 20; p++) xo[p] = pack_bf16(o[2 * p], o[2 * p + 1]);
    as2[n] = s;
    ad2[n] = t;
}

// ===========================================================================
// Layer-2 aggregation (pull). Wave per dst; pairs p=0..19 active for data,
// all lanes help with denominator of their half. Writes d_out directly.
// ===========================================================================
__global__ __launch_bounds__(256) void k_agg2(
    const int* __restrict__ row_ptr, const int* __restrict__ csr_src,
    const float* __restrict__ as2, const float* __restrict__ ad2,
    const unsigned* __restrict__ xl2b, const float* __restrict__ b2,
    float* __restrict__ out, int N)
{
    int d = blockIdx.x * 4 + (threadIdx.x >> 6);
    int lane = threadIdx.x & 63;
    if (d >= N) return;
    int half = lane >> 5;
    int p = lane & 31;          // channel pair, active if p<20

    int beg = row_ptr[d];
    int end = row_ptr[d + 1];
    float add = ad2[d];
    bool act = (p < 20);
    int pc = act ? p : 0;       // clamp so inactive lanes load a valid addr

    float ax0 = 0.f, ay0 = 0.f, dn0 = 0.f;
    float ax1 = 0.f, ay1 = 0.f, dn1 = 0.f;
    int i = beg + half;
    for (; i + 2 < end; i += 4) {
        int s0 = csr_src[i];
        int s1 = csr_src[i + 2];
        float al0 = as2[s0] + add;
        float al1 = as2[s1] + add;
        unsigned k0 = xl2b[(size_t)s0 * 20 + pc];
        unsigned k1 = xl2b[(size_t)s1 * 20 + pc];
        al0 = al0 > 0.f ? al0 : NEG_SLOPE * al0;
        al1 = al1 > 0.f ? al1 : NEG_SLOPE * al1;
        float e0 = __expf(al0);
        float e1 = __expf(al1);
        ax0 = fmaf(e0, bf_lo(k0), ax0); ay0 = fmaf(e0, bf_hi(k0), ay0); dn0 += e0;
        ax1 = fmaf(e1, bf_lo(k1), ax1); ay1 = fmaf(e1, bf_hi(k1), ay1); dn1 += e1;
    }
    if (i < end) {
        int s0 = csr_src[i];
        float al0 = as2[s0] + add;
        unsigned k0 = xl2b[(size_t)s0 * 20 + pc];
        al0 = al0 > 0.f ? al0 : NEG_SLOPE * al0;
        float e0 = __expf(al0);
        ax0 = fmaf(e0, bf_lo(k0), ax0); ay0 = fmaf(e0, bf_hi(k0), ay0); dn0 += e0;
    }

    float ax = ax0 + ax1, ay = ay0 + ay1, den = dn0 + dn1;
    ax += __shfl_xor(ax, 32);
    ay += __shfl_xor(ay, 32);
    den += __shfl_xor(den, 32);

    if (half == 0 && act) {
        float inv = 1.0f / (den + GAT_EPS);
        float2 bv = ((const float2*)b2)[p];
        ((float2*)(out + (size_t)d * 40))[p] =
            make_float2(ax * inv + bv.x, ay * inv + bv.y);
    }
}

extern "C" void kernel_launch(void* const* d_in, const int* in_sizes, int n_in,
                              void* d_out, int out_size, void* d_ws, size_t ws_size,
                              hipStream_t stream) {
    const float* x      = (const float*)d_in[0];
    const int*   ei     = (const int*)d_in[1];     // int32 on device
    const float* W1     = (const float*)d_in[2];
    const float* a_src1 = (const float*)d_in[3];
    const float* a_dst1 = (const float*)d_in[4];
    const float* b1     = (const float*)d_in[5];
    const float* W2     = (const float*)d_in[6];
    const float* a_src2 = (const float*)d_in[7];
    const float* a_dst2 = (const float*)d_in[8];
    const float* b2     = (const float*)d_in[9];

    int F = in_sizes[2] / 64;      // 128
    int N = in_sizes[0] / F;       // 100000
    int E = in_sizes[1] / 2;       // 1600000
    int Etot = E + N;
    int NB = (N + 255) / 256;      // <=1024 (k_scan_b capacity)

    // Workspace (4-byte words). Peak ~48 MB.
    unsigned* xl1b   = (unsigned*)d_ws;                    // N*32 uints
    float*    h1     = (float*)(xl1b + (size_t)N * 32);    // N*64
    float*    as1    = h1 + (size_t)N * 64;                // N*8
    float*    ad1    = as1 + (size_t)N * 8;                // N*8
    int*      deg    = (int*)(ad1 + (size_t)N * 8);        // N
    int*      row_ptr= deg + N;                            // N+1
    int*      cursor = row_ptr + (N + 1);                  // N
    int*      bsum   = cursor + N;                         // 1024
    int*      boff   = bsum + 1024;                        // 1024
    int*      csr_src= boff + 1024;                        // Etot
    // Aliases (live only after k_agg1; originals dead by then):
    unsigned* xl2b   = xl1b;                               // N*20 <= N*32
    float*    as2    = as1;                                // N
    float*    ad2    = ad1;                                // N

    // ---- CSR build (shared by both layers) ----
    hipMemsetAsync(deg, 0, (size_t)N * sizeof(int), stream);
    k_hist   <<<(Etot + 255) / 256, 256, 0, stream>>>(ei, E, N, deg);
    k_scan_a <<<NB, 256, 0, stream>>>(deg, bsum, N);
    k_scan_b <<<1, 1024, 0, stream>>>(bsum, boff, NB);
    k_scan_c <<<NB, 256, 0, stream>>>(deg, boff, row_ptr, cursor, N, Etot);
    k_scatter<<<(Etot + 255) / 256, 256, 0, stream>>>(ei, E, N, cursor, csr_src);

    // ---- Layer 1 ----
    k_gemm1<<<(N + 255) / 256, 256, 0, stream>>>(x, W1, a_src1, a_dst1,
                                                 xl1b, as1, ad1, N, F);
    k_agg1 <<<(N + 3) / 4, 256, 0, stream>>>(row_ptr, csr_src, as1, ad1,
                                             xl1b, b1, h1, N);

    // ---- Layer 2 ----
    k_node2<<<(N + 255) / 256, 256, 0, stream>>>(h1, W2, a_src2, a_dst2,
                                                 xl2b, as2, ad2, N);
    k_agg2 <<<(N + 3) / 4, 256, 0, stream>>>(row_ptr, csr_src, as2, ad2,
                                             xl2b, b2, (float*)d_out, N);
}